// Round 4
// baseline (205.499 us; speedup 1.0000x reference)
//
#include <hip/hip_runtime.h>
#include <float.h>
#include <math.h>

#define BB 32
#define NN 1024
#define DD 128
#define KK 5

typedef __attribute__((ext_vector_type(8))) short bf16x8;
typedef __attribute__((ext_vector_type(4))) float f32x4;

// rtne f32->bf16 bit trick (no NaN/inf in this problem)
__device__ __forceinline__ unsigned short f2bf(float f) {
    unsigned int u = __float_as_uint(f);
    return (unsigned short)((u + 0x7FFFu + ((u >> 16) & 1u)) >> 16);
}
__device__ __forceinline__ float bf2f(unsigned short h) {
    return __uint_as_float(((unsigned int)h) << 16);
}

// ---- 1. fused: row L2-normalize + 3-limb bf16 split (h,m,l planes) ------
__global__ __launch_bounds__(256) void k_norm(const float* __restrict__ x,
                                              unsigned short* __restrict__ ph,
                                              unsigned short* __restrict__ pm,
                                              unsigned short* __restrict__ pl) {
    int row  = blockIdx.x * 4 + (threadIdx.x >> 6);
    int lane = threadIdx.x & 63;
    float2 v = *reinterpret_cast<const float2*>(x + (size_t)row * DD + lane * 2);
    float ss = v.x * v.x + v.y * v.y;
#pragma unroll
    for (int o = 32; o >= 1; o >>= 1) ss += __shfl_xor(ss, o);
    float inv = 1.0f / fmaxf(sqrtf(ss), 1e-12f);
    float y0 = v.x * inv, y1 = v.y * inv;

    unsigned short h0 = f2bf(y0);             float r0 = y0 - bf2f(h0);
    unsigned short m0 = f2bf(r0);             float s0 = r0 - bf2f(m0);
    unsigned short l0 = f2bf(s0);
    unsigned short h1 = f2bf(y1);             float r1 = y1 - bf2f(h1);
    unsigned short m1 = f2bf(r1);             float s1 = r1 - bf2f(m1);
    unsigned short l1 = f2bf(s1);

    size_t o = (size_t)row * DD + lane * 2;
    *reinterpret_cast<unsigned int*>(ph + o) = (unsigned int)h0 | ((unsigned int)h1 << 16);
    *reinterpret_cast<unsigned int*>(pm + o) = (unsigned int)m0 | ((unsigned int)m1 << 16);
    *reinterpret_cast<unsigned int*>(pl + o) = (unsigned int)l0 | ((unsigned int)l1 << 16);
}

// ---- 2. sim via MFMA: 6-term limb GEMM, one 128x128 tile per block ------
// no LDS: fragments load straight from the L2-resident bf16 planes.
// wave w covers 64x64 quadrant (wr,wc); 4x4 frags of 16x16x32.
__global__ __launch_bounds__(256, 2) void k_sim(const unsigned short* __restrict__ ph,
                                                const unsigned short* __restrict__ pm,
                                                const unsigned short* __restrict__ pl,
                                                float* __restrict__ sim, int b0) {
    int t  = blockIdx.x;
    int bl = t >> 6;
    int tt = t & 63;
    int R  = (tt >> 3) << 7;
    int Cc = (tt & 7) << 7;
    int wv   = threadIdx.x >> 6;
    int lane = threadIdx.x & 63;
    int wr = (wv >> 1) << 6;
    int wc = (wv & 1) << 6;

    size_t base = (size_t)(b0 + bl) * NN;
    size_t oA = (base + R + wr + (lane & 15)) * DD + ((lane >> 4) << 3);
    size_t oB = (base + Cc + wc + (lane & 15)) * DD + ((lane >> 4) << 3);

    f32x4 acc[4][4];
#pragma unroll
    for (int i = 0; i < 4; ++i)
#pragma unroll
        for (int j = 0; j < 4; ++j) acc[i][j] = (f32x4){0.f, 0.f, 0.f, 0.f};

    for (int ks = 0; ks < 4; ++ks) {
        int ko = ks << 5;
        bf16x8 bh[4], bm[4], blo[4];
#pragma unroll
        for (int cp = 0; cp < 4; ++cp) {
            size_t ob = oB + (size_t)cp * 16 * DD + ko;
            bh[cp]  = *reinterpret_cast<const bf16x8*>(ph + ob);
            bm[cp]  = *reinterpret_cast<const bf16x8*>(pm + ob);
            blo[cp] = *reinterpret_cast<const bf16x8*>(pl + ob);
        }
#pragma unroll
        for (int rp = 0; rp < 4; ++rp) {
            size_t oa = oA + (size_t)rp * 16 * DD + ko;
            bf16x8 ah  = *reinterpret_cast<const bf16x8*>(ph + oa);
            bf16x8 am  = *reinterpret_cast<const bf16x8*>(pm + oa);
            bf16x8 al  = *reinterpret_cast<const bf16x8*>(pl + oa);
#pragma unroll
            for (int cp = 0; cp < 4; ++cp) {
                f32x4 c = acc[rp][cp];
                c = __builtin_amdgcn_mfma_f32_16x16x32_bf16(ah, bh[cp],  c, 0, 0, 0);
                c = __builtin_amdgcn_mfma_f32_16x16x32_bf16(ah, bm[cp],  c, 0, 0, 0);
                c = __builtin_amdgcn_mfma_f32_16x16x32_bf16(am, bh[cp],  c, 0, 0, 0);
                c = __builtin_amdgcn_mfma_f32_16x16x32_bf16(ah, blo[cp], c, 0, 0, 0);
                c = __builtin_amdgcn_mfma_f32_16x16x32_bf16(al, bh[cp],  c, 0, 0, 0);
                c = __builtin_amdgcn_mfma_f32_16x16x32_bf16(am, bm[cp],  c, 0, 0, 0);
                acc[rp][cp] = c;
            }
        }
    }

    // C layout: col = lane&15, row = (lane>>4)*4 + reg
    float* Cb = sim + (size_t)bl * NN * NN;
    int crow = R + wr + ((lane >> 4) << 2);
    int ccol = Cc + wc + (lane & 15);
#pragma unroll
    for (int rp = 0; rp < 4; ++rp)
#pragma unroll
        for (int reg = 0; reg < 4; ++reg) {
            size_t rowo = (size_t)(crow + rp * 16 + reg) * NN + ccol;
#pragma unroll
            for (int cp = 0; cp < 4; ++cp)
                Cb[rowo + cp * 16] = acc[rp][cp][reg];
        }
}

// ---------------- 3. top-5 per row (wave per row) ------------------------
__global__ __launch_bounds__(256) void k_topk(const float* __restrict__ sim,
                                              int* __restrict__ idx, int b0) {
    int lrow = blockIdx.x * 4 + (threadIdx.x >> 6);
    int lane = threadIdx.x & 63;
    const float* sr = sim + (size_t)lrow * NN;
    int i = lrow & (NN - 1);

    float v[16];
#pragma unroll
    for (int q = 0; q < 4; ++q) {
        float4 f = *reinterpret_cast<const float4*>(sr + lane * 16 + q * 4);
        v[q * 4 + 0] = f.x; v[q * 4 + 1] = f.y; v[q * 4 + 2] = f.z; v[q * 4 + 3] = f.w;
    }
    if ((i >> 4) == lane) {
        int s = i & 15;
#pragma unroll
        for (int j = 0; j < 16; ++j) if (j == s) v[j] = -FLT_MAX;
    }
    int* op = idx + ((size_t)b0 * NN + lrow) * KK;
#pragma unroll
    for (int t = 0; t < KK; ++t) {
        float bv = v[0]; int bj = 0;
#pragma unroll
        for (int j = 1; j < 16; ++j) if (v[j] > bv) { bv = v[j]; bj = j; }
        int bm = (lane << 4) + bj;
#pragma unroll
        for (int o = 1; o < 64; o <<= 1) {
            float ov = __shfl_xor(bv, o);
            int   om = __shfl_xor(bm, o);
            if (ov > bv || (ov == bv && om < bm)) { bv = ov; bm = om; }
        }
        if ((bm >> 4) == lane) {
            int s = bm & 15;
#pragma unroll
            for (int j = 0; j < 16; ++j) if (j == s) v[j] = -FLT_MAX;
        }
        if (lane == 0) op[t] = bm;
    }
}

// ---- 4. fused gcn: out = res + relu( agg(h,idx) @ W^T + bias ) ----------
// 64-row tiles (512 blocks, ~3/CU). agg during A staging.
#define SW(c) ((c) + 4 * ((c) >> 5))
#define LDW 140

__global__ __launch_bounds__(256, 3) void k_gcn(const float* __restrict__ h,
                                                const int* __restrict__ idx,
                                                const float* __restrict__ W,
                                                const float* __restrict__ bias,
                                                const float* __restrict__ res,
                                                float* __restrict__ out) {
    int rt = blockIdx.x << 6;
    __shared__ float As[64][68];
    __shared__ float Bs[64][LDW];
    int tid = threadIdx.x;
    int tr  = (tid >> 4) << 2;
    int tc  = (tid & 15) << 3;
    int stc = SW(tc);

    float acc[4][8];
#pragma unroll
    for (int i = 0; i < 4; ++i)
#pragma unroll
        for (int j = 0; j < 8; ++j) acc[i][j] = 0.f;

#pragma unroll
    for (int kc = 0; kc < 2; ++kc) {
        if (kc) __syncthreads();
        {   // stage aggregated A (64 rows x 64 k)
            int kv = tid & 15, r0 = tid >> 4;
            int colf = (kc << 6) + (kv << 2);
#pragma unroll
            for (int p = 0; p < 4; ++p) {
                int lrow = r0 + (p << 4);
                int grow = rt + lrow;
                const int* ip = idx + (size_t)grow * KK;
                const float* hb = h + (((size_t)grow >> 10) << 10) * DD;
                float4 v = *reinterpret_cast<const float4*>(h + (size_t)grow * DD + colf);
#pragma unroll
                for (int t = 0; t < KK; ++t) {
                    const float4 u = *reinterpret_cast<const float4*>(hb + (size_t)ip[t] * DD + colf);
                    v.x += u.x; v.y += u.y; v.z += u.z; v.w += u.w;
                }
                const float c = 1.0f / 6.0f;
                int k = kv << 2;
                As[k + 0][lrow] = v.x * c; As[k + 1][lrow] = v.y * c;
                As[k + 2][lrow] = v.z * c; As[k + 3][lrow] = v.w * c;
            }
        }
        {   // stage W (128 h-cols x 64 k)
            int kv = tid & 15, r0 = tid >> 4;
            const float* g = W + kc * 64;
#pragma unroll
            for (int p = 0; p < 8; ++p) {
                int r = r0 + (p << 4);
                const float4 v = *reinterpret_cast<const float4*>(g + (size_t)r * DD + (kv << 2));
                int k = kv << 2, row = SW(r);
                Bs[k + 0][row] = v.x; Bs[k + 1][row] = v.y;
                Bs[k + 2][row] = v.z; Bs[k + 3][row] = v.w;
            }
        }
        __syncthreads();
#pragma unroll 4
        for (int k = 0; k < 64; ++k) {
            const float4 a  = *reinterpret_cast<const float4*>(&As[k][tr]);
            const float4 b0 = *reinterpret_cast<const float4*>(&Bs[k][stc]);
            const float4 b1 = *reinterpret_cast<const float4*>(&Bs[k][stc + 4]);
            const float av[4] = {a.x, a.y, a.z, a.w};
            const float bw[8] = {b0.x, b0.y, b0.z, b0.w, b1.x, b1.y, b1.z, b1.w};
#pragma unroll
            for (int ii = 0; ii < 4; ++ii)
#pragma unroll
                for (int jj = 0; jj < 8; ++jj)
                    acc[ii][jj] = fmaf(av[ii], bw[jj], acc[ii][jj]);
        }
    }
    const float4 bz0 = *reinterpret_cast<const float4*>(bias + tc);
    const float4 bz1 = *reinterpret_cast<const float4*>(bias + tc + 4);
    const float bb[8] = {bz0.x, bz0.y, bz0.z, bz0.w, bz1.x, bz1.y, bz1.z, bz1.w};
#pragma unroll
    for (int i = 0; i < 4; ++i) {
        size_t ro = (size_t)(rt + tr + i) * DD + tc;
        const float4 r0 = *reinterpret_cast<const float4*>(res + ro);
        const float4 r1 = *reinterpret_cast<const float4*>(res + ro + 4);
        float4 o0, o1;
        o0.x = r0.x + fmaxf(acc[i][0] + bb[0], 0.f);
        o0.y = r0.y + fmaxf(acc[i][1] + bb[1], 0.f);
        o0.z = r0.z + fmaxf(acc[i][2] + bb[2], 0.f);
        o0.w = r0.w + fmaxf(acc[i][3] + bb[3], 0.f);
        o1.x = r1.x + fmaxf(acc[i][4] + bb[4], 0.f);
        o1.y = r1.y + fmaxf(acc[i][5] + bb[5], 0.f);
        o1.z = r1.z + fmaxf(acc[i][6] + bb[6], 0.f);
        o1.w = r1.w + fmaxf(acc[i][7] + bb[7], 0.f);
        *reinterpret_cast<float4*>(out + ro)     = o0;
        *reinterpret_cast<float4*>(out + ro + 4) = o1;
    }
}

extern "C" void kernel_launch(void* const* d_in, const int* in_sizes, int n_in,
                              void* d_out, int out_size, void* d_ws, size_t ws_size,
                              hipStream_t stream) {
    const float* x  = (const float*)d_in[0];
    const float* W1 = (const float*)d_in[1];
    const float* b1 = (const float*)d_in[2];
    const float* W2 = (const float*)d_in[3];
    const float* b2 = (const float*)d_in[4];
    float* out = (float*)d_out;

    char* ws = (char*)d_ws;
    size_t pl_b  = (size_t)BB * NN * DD * 2;      // one bf16 plane
    size_t h1_b  = (size_t)BB * NN * DD * 4;
    size_t idx_b = (size_t)BB * NN * KK * 4;
    unsigned short* ph = (unsigned short*)ws;  ws += pl_b;
    unsigned short* pm = (unsigned short*)ws;  ws += pl_b;
    unsigned short* pl = (unsigned short*)ws;  ws += pl_b;
    float* h1  = (float*)ws;                   ws += h1_b;
    int*   idx = (int*)ws;                     ws += idx_b;
    float* sim = (float*)ws;
    size_t fixed = 3 * pl_b + h1_b + idx_b;
    size_t sim_avail = (ws_size > fixed) ? (ws_size - fixed) : 0;
    int SB = (int)(sim_avail / ((size_t)NN * NN * 4));
    if (SB > BB) SB = BB;
    if (SB < 1) SB = 1;

    k_norm<<<BB * NN / 4, 256, 0, stream>>>(x, ph, pm, pl);
    for (int b0 = 0; b0 < BB; b0 += SB) {
        int sb = (SB < BB - b0) ? SB : (BB - b0);
        k_sim<<<sb * 64, 256, 0, stream>>>(ph, pm, pl, sim, b0);
        k_topk<<<sb * NN / 4, 256, 0, stream>>>(sim, idx, b0);
    }
    k_gcn<<<BB * NN / 64, 256, 0, stream>>>(x,  idx, W1, b1, x,  h1);
    k_gcn<<<BB * NN / 64, 256, 0, stream>>>(h1, idx, W2, b2, h1, out);
}

// Round 5
// 172.065 us; speedup vs baseline: 1.1943x; 1.1943x over previous
//
#include <hip/hip_runtime.h>
#include <float.h>
#include <math.h>

#define BB 32
#define NN 1024
#define DD 128
#define KK 5

typedef __attribute__((ext_vector_type(8))) short bf16x8;
typedef __attribute__((ext_vector_type(4))) float f32x4;

// rtne f32->bf16 bit trick (no NaN/inf in this problem)
__device__ __forceinline__ unsigned short f2bf(float f) {
    unsigned int u = __float_as_uint(f);
    return (unsigned short)((u + 0x7FFFu + ((u >> 16) & 1u)) >> 16);
}
__device__ __forceinline__ float bf2f(unsigned short h) {
    return __uint_as_float(((unsigned int)h) << 16);
}

// ---- 1. fused: row L2-normalize + 3-limb bf16 split (h,m,l planes) ------
__global__ __launch_bounds__(256) void k_norm(const float* __restrict__ x,
                                              unsigned short* __restrict__ ph,
                                              unsigned short* __restrict__ pm,
                                              unsigned short* __restrict__ pl) {
    int row  = blockIdx.x * 4 + (threadIdx.x >> 6);
    int lane = threadIdx.x & 63;
    float2 v = *reinterpret_cast<const float2*>(x + (size_t)row * DD + lane * 2);
    float ss = v.x * v.x + v.y * v.y;
#pragma unroll
    for (int o = 32; o >= 1; o >>= 1) ss += __shfl_xor(ss, o);
    float inv = 1.0f / fmaxf(sqrtf(ss), 1e-12f);
    float y0 = v.x * inv, y1 = v.y * inv;

    unsigned short h0 = f2bf(y0);             float r0 = y0 - bf2f(h0);
    unsigned short m0 = f2bf(r0);             float s0 = r0 - bf2f(m0);
    unsigned short l0 = f2bf(s0);
    unsigned short h1 = f2bf(y1);             float r1 = y1 - bf2f(h1);
    unsigned short m1 = f2bf(r1);             float s1 = r1 - bf2f(m1);
    unsigned short l1 = f2bf(s1);

    size_t o = (size_t)row * DD + lane * 2;
    *reinterpret_cast<unsigned int*>(ph + o) = (unsigned int)h0 | ((unsigned int)h1 << 16);
    *reinterpret_cast<unsigned int*>(pm + o) = (unsigned int)m0 | ((unsigned int)m1 << 16);
    *reinterpret_cast<unsigned int*>(pl + o) = (unsigned int)l0 | ((unsigned int)l1 << 16);
}

// stage one plane's 128 rows x 32 k chunk into LDS (rows relative rowbase)
__device__ __forceinline__ void stage_plane(const unsigned short* __restrict__ g,
                                            unsigned short (*s)[40], int tid,
                                            size_t rowbase, int c) {
#pragma unroll
    for (int hh = 0; hh < 2; ++hh) {
        int u = tid + (hh << 8);
        int row = u >> 2, q = u & 3;
        const float4 v = *reinterpret_cast<const float4*>(
            g + (rowbase + row) * DD + (c << 5) + (q << 3));
        *reinterpret_cast<float4*>(&s[row][q << 3]) = v;
    }
}

// ---- 2. sim via MFMA: 6-term limb GEMM, upper-tri 128x128 tiles ---------
// LDS-staged (6 planes x [128][40] bf16, 60KB), mirror-store for symmetry.
__global__ __launch_bounds__(256, 2) void k_sim(const unsigned short* __restrict__ ph,
                                                const unsigned short* __restrict__ pm,
                                                const unsigned short* __restrict__ pl,
                                                float* __restrict__ sim, int b0) {
    int t  = blockIdx.x;
    int bl = t / 36;
    int p  = t - bl * 36;
    int ti = 0;
    while (p >= 8 - ti) { p -= 8 - ti; ++ti; }
    int tj = ti + p;
    int R  = ti << 7, Cc = tj << 7;

    __shared__ unsigned short Ah[128][40], Am[128][40], Al[128][40];
    __shared__ unsigned short Bh[128][40], Bm[128][40], Bl[128][40];

    int tid  = threadIdx.x;
    int wv   = tid >> 6;
    int lane = tid & 63;
    int wr = (wv >> 1) << 6;
    int wc = (wv & 1) << 6;

    size_t base  = (size_t)(b0 + bl) * NN;
    size_t rbA = base + R, rbB = base + Cc;

    f32x4 acc[4][4];
#pragma unroll
    for (int i = 0; i < 4; ++i)
#pragma unroll
        for (int j = 0; j < 4; ++j) acc[i][j] = (f32x4){0.f, 0.f, 0.f, 0.f};

    int kk = (lane >> 4) << 3;      // k-offset within chunk for fragments
    int fr = lane & 15;             // fragment row/col within 16-group

    for (int c = 0; c < 4; ++c) {
        if (c) __syncthreads();
        stage_plane(ph, Ah, tid, rbA, c);
        stage_plane(pm, Am, tid, rbA, c);
        stage_plane(pl, Al, tid, rbA, c);
        stage_plane(ph, Bh, tid, rbB, c);
        stage_plane(pm, Bm, tid, rbB, c);
        stage_plane(pl, Bl, tid, rbB, c);
        __syncthreads();

        bf16x8 bh[4], bm[4], blo[4];
#pragma unroll
        for (int cp = 0; cp < 4; ++cp) {
            int rb = wc + cp * 16 + fr;
            bh[cp]  = *reinterpret_cast<const bf16x8*>(&Bh[rb][kk]);
            bm[cp]  = *reinterpret_cast<const bf16x8*>(&Bm[rb][kk]);
            blo[cp] = *reinterpret_cast<const bf16x8*>(&Bl[rb][kk]);
        }
#pragma unroll
        for (int rp = 0; rp < 4; ++rp) {
            int ra = wr + rp * 16 + fr;
            bf16x8 ah = *reinterpret_cast<const bf16x8*>(&Ah[ra][kk]);
            bf16x8 am = *reinterpret_cast<const bf16x8*>(&Am[ra][kk]);
            bf16x8 al = *reinterpret_cast<const bf16x8*>(&Al[ra][kk]);
#pragma unroll
            for (int cp = 0; cp < 4; ++cp) {
                f32x4 cacc = acc[rp][cp];
                cacc = __builtin_amdgcn_mfma_f32_16x16x32_bf16(ah, bh[cp],  cacc, 0, 0, 0);
                cacc = __builtin_amdgcn_mfma_f32_16x16x32_bf16(ah, bm[cp],  cacc, 0, 0, 0);
                cacc = __builtin_amdgcn_mfma_f32_16x16x32_bf16(am, bh[cp],  cacc, 0, 0, 0);
                cacc = __builtin_amdgcn_mfma_f32_16x16x32_bf16(ah, blo[cp], cacc, 0, 0, 0);
                cacc = __builtin_amdgcn_mfma_f32_16x16x32_bf16(al, bh[cp],  cacc, 0, 0, 0);
                cacc = __builtin_amdgcn_mfma_f32_16x16x32_bf16(am, bm[cp],  cacc, 0, 0, 0);
                acc[rp][cp] = cacc;
            }
        }
    }

    // C layout: col = lane&15, row = (lane>>4)*4 + reg
    float* Cb = sim + (size_t)bl * NN * NN;
    int crow = R + wr + ((lane >> 4) << 2);
    int ccol = Cc + wc + fr;
#pragma unroll
    for (int rp = 0; rp < 4; ++rp)
#pragma unroll
        for (int reg = 0; reg < 4; ++reg) {
            size_t rowo = (size_t)(crow + rp * 16 + reg) * NN + ccol;
#pragma unroll
            for (int cp = 0; cp < 4; ++cp)
                Cb[rowo + cp * 16] = acc[rp][cp][reg];
        }
    if (ti != tj) {  // mirror: 4 regs are consecutive columns -> float4
#pragma unroll
        for (int cp = 0; cp < 4; ++cp) {
            size_t mr = (size_t)(Cc + wc + cp * 16 + fr) * NN + (R + wr + ((lane >> 4) << 2));
#pragma unroll
            for (int rp = 0; rp < 4; ++rp)
                *reinterpret_cast<float4*>(&Cb[mr + rp * 16]) =
                    make_float4(acc[rp][cp][0], acc[rp][cp][1], acc[rp][cp][2], acc[rp][cp][3]);
        }
    }
}

// ---------------- 3. top-5 per row (wave per row) ------------------------
__global__ __launch_bounds__(256) void k_topk(const float* __restrict__ sim,
                                              int* __restrict__ idx, int b0) {
    int lrow = blockIdx.x * 4 + (threadIdx.x >> 6);
    int lane = threadIdx.x & 63;
    const float* sr = sim + (size_t)lrow * NN;
    int i = lrow & (NN - 1);

    float v[16];
#pragma unroll
    for (int q = 0; q < 4; ++q) {
        float4 f = *reinterpret_cast<const float4*>(sr + lane * 16 + q * 4);
        v[q * 4 + 0] = f.x; v[q * 4 + 1] = f.y; v[q * 4 + 2] = f.z; v[q * 4 + 3] = f.w;
    }
    if ((i >> 4) == lane) {
        int s = i & 15;
#pragma unroll
        for (int j = 0; j < 16; ++j) if (j == s) v[j] = -FLT_MAX;
    }
    int* op = idx + ((size_t)b0 * NN + lrow) * KK;
#pragma unroll
    for (int t = 0; t < KK; ++t) {
        float bv = v[0]; int bj = 0;
#pragma unroll
        for (int j = 1; j < 16; ++j) if (v[j] > bv) { bv = v[j]; bj = j; }
        int bm = (lane << 4) + bj;
#pragma unroll
        for (int o = 1; o < 64; o <<= 1) {
            float ov = __shfl_xor(bv, o);
            int   om = __shfl_xor(bm, o);
            if (ov > bv || (ov == bv && om < bm)) { bv = ov; bm = om; }
        }
        if ((bm >> 4) == lane) {
            int s = bm & 15;
#pragma unroll
            for (int j = 0; j < 16; ++j) if (j == s) v[j] = -FLT_MAX;
        }
        if (lane == 0) op[t] = bm;
    }
}

// ---- 4. fused gcn: out = res + relu( agg(h,idx) @ W^T + bias ) ----------
#define SW(c) ((c) + 4 * ((c) >> 5))
#define LDW 140

__global__ __launch_bounds__(256, 3) void k_gcn(const float* __restrict__ h,
                                                const int* __restrict__ idx,
                                                const float* __restrict__ W,
                                                const float* __restrict__ bias,
                                                const float* __restrict__ res,
                                                float* __restrict__ out) {
    int rt = blockIdx.x << 6;
    __shared__ float As[64][68];
    __shared__ float Bs[64][LDW];
    int tid = threadIdx.x;
    int tr  = (tid >> 4) << 2;
    int tc  = (tid & 15) << 3;
    int stc = SW(tc);

    float acc[4][8];
#pragma unroll
    for (int i = 0; i < 4; ++i)
#pragma unroll
        for (int j = 0; j < 8; ++j) acc[i][j] = 0.f;

#pragma unroll
    for (int kc = 0; kc < 2; ++kc) {
        if (kc) __syncthreads();
        {
            int kv = tid & 15, r0 = tid >> 4;
            int colf = (kc << 6) + (kv << 2);
#pragma unroll
            for (int p = 0; p < 4; ++p) {
                int lrow = r0 + (p << 4);
                int grow = rt + lrow;
                const int* ip = idx + (size_t)grow * KK;
                const float* hb = h + (((size_t)grow >> 10) << 10) * DD;
                float4 v = *reinterpret_cast<const float4*>(h + (size_t)grow * DD + colf);
#pragma unroll
                for (int t = 0; t < KK; ++t) {
                    const float4 u = *reinterpret_cast<const float4*>(hb + (size_t)ip[t] * DD + colf);
                    v.x += u.x; v.y += u.y; v.z += u.z; v.w += u.w;
                }
                const float c = 1.0f / 6.0f;
                int k = kv << 2;
                As[k + 0][lrow] = v.x * c; As[k + 1][lrow] = v.y * c;
                As[k + 2][lrow] = v.z * c; As[k + 3][lrow] = v.w * c;
            }
        }
        {
            int kv = tid & 15, r0 = tid >> 4;
            const float* g = W + kc * 64;
#pragma unroll
            for (int p = 0; p < 8; ++p) {
                int r = r0 + (p << 4);
                const float4 v = *reinterpret_cast<const float4*>(g + (size_t)r * DD + (kv << 2));
                int k = kv << 2, row = SW(r);
                Bs[k + 0][row] = v.x; Bs[k + 1][row] = v.y;
                Bs[k + 2][row] = v.z; Bs[k + 3][row] = v.w;
            }
        }
        __syncthreads();
#pragma unroll 4
        for (int k = 0; k < 64; ++k) {
            const float4 a  = *reinterpret_cast<const float4*>(&As[k][tr]);
            const float4 b0 = *reinterpret_cast<const float4*>(&Bs[k][stc]);
            const float4 b1 = *reinterpret_cast<const float4*>(&Bs[k][stc + 4]);
            const float av[4] = {a.x, a.y, a.z, a.w};
            const float bw[8] = {b0.x, b0.y, b0.z, b0.w, b1.x, b1.y, b1.z, b1.w};
#pragma unroll
            for (int ii = 0; ii < 4; ++ii)
#pragma unroll
                for (int jj = 0; jj < 8; ++jj)
                    acc[ii][jj] = fmaf(av[ii], bw[jj], acc[ii][jj]);
        }
    }
    const float4 bz0 = *reinterpret_cast<const float4*>(bias + tc);
    const float4 bz1 = *reinterpret_cast<const float4*>(bias + tc + 4);
    const float bb[8] = {bz0.x, bz0.y, bz0.z, bz0.w, bz1.x, bz1.y, bz1.z, bz1.w};
#pragma unroll
    for (int i = 0; i < 4; ++i) {
        size_t ro = (size_t)(rt + tr + i) * DD + tc;
        const float4 r0 = *reinterpret_cast<const float4*>(res + ro);
        const float4 r1 = *reinterpret_cast<const float4*>(res + ro + 4);
        float4 o0, o1;
        o0.x = r0.x + fmaxf(acc[i][0] + bb[0], 0.f);
        o0.y = r0.y + fmaxf(acc[i][1] + bb[1], 0.f);
        o0.z = r0.z + fmaxf(acc[i][2] + bb[2], 0.f);
        o0.w = r0.w + fmaxf(acc[i][3] + bb[3], 0.f);
        o1.x = r1.x + fmaxf(acc[i][4] + bb[4], 0.f);
        o1.y = r1.y + fmaxf(acc[i][5] + bb[5], 0.f);
        o1.z = r1.z + fmaxf(acc[i][6] + bb[6], 0.f);
        o1.w = r1.w + fmaxf(acc[i][7] + bb[7], 0.f);
        *reinterpret_cast<float4*>(out + ro)     = o0;
        *reinterpret_cast<float4*>(out + ro + 4) = o1;
    }
}

extern "C" void kernel_launch(void* const* d_in, const int* in_sizes, int n_in,
                              void* d_out, int out_size, void* d_ws, size_t ws_size,
                              hipStream_t stream) {
    const float* x  = (const float*)d_in[0];
    const float* W1 = (const float*)d_in[1];
    const float* b1 = (const float*)d_in[2];
    const float* W2 = (const float*)d_in[3];
    const float* b2 = (const float*)d_in[4];
    float* out = (float*)d_out;

    char* ws = (char*)d_ws;
    size_t pl_b  = (size_t)BB * NN * DD * 2;
    size_t h1_b  = (size_t)BB * NN * DD * 4;
    size_t idx_b = (size_t)BB * NN * KK * 4;
    unsigned short* ph = (unsigned short*)ws;  ws += pl_b;
    unsigned short* pm = (unsigned short*)ws;  ws += pl_b;
    unsigned short* pl = (unsigned short*)ws;  ws += pl_b;
    float* h1  = (float*)ws;                   ws += h1_b;
    int*   idx = (int*)ws;                     ws += idx_b;
    float* sim = (float*)ws;
    size_t fixed = 3 * pl_b + h1_b + idx_b;
    size_t sim_avail = (ws_size > fixed) ? (ws_size - fixed) : 0;
    int SB = (int)(sim_avail / ((size_t)NN * NN * 4));
    if (SB > BB) SB = BB;
    if (SB < 1) SB = 1;

    k_norm<<<BB * NN / 4, 256, 0, stream>>>(x, ph, pm, pl);
    for (int b0 = 0; b0 < BB; b0 += SB) {
        int sb = (SB < BB - b0) ? SB : (BB - b0);
        k_sim<<<sb * 36, 256, 0, stream>>>(ph, pm, pl, sim, b0);
        k_topk<<<sb * NN / 4, 256, 0, stream>>>(sim, idx, b0);
    }
    k_gcn<<<BB * NN / 64, 256, 0, stream>>>(x,  idx, W1, b1, x,  h1);
    k_gcn<<<BB * NN / 64, 256, 0, stream>>>(h1, idx, W2, b2, h1, out);
}